// Round 1
// baseline (300.116 us; speedup 1.0000x reference)
//
#include <hip/hip_runtime.h>

// Problem constants (from reference)
#define BB   128        // batch
#define DD   2048       // input dim (= K)
#define NN   2048       // neurons per layer
#define LL   4          // layers
#define OUTN 1024       // output gather size

// GEMM tiling
#define NSPLIT 8                 // K-split factor -> 8*64 = 512 blocks
#define KRANGE (DD / NSPLIT)     // 256 k per block
#define KC     32                // k-chunk staged in LDS
#define NTILE  32                // n per block (wave handles 8 n, lane handles 2 b)

// ---------------------------------------------------------------------------
// Layer-0 transpose-gather: At[k][b] = x[b, axon_idx0[k]]
// ---------------------------------------------------------------------------
__global__ __launch_bounds__(256) void gather0_kernel(
    const float* __restrict__ x, const int* __restrict__ idx0,
    float* __restrict__ At)
{
    int i = blockIdx.x * 256 + threadIdx.x;   // over DD*BB = 262144
    int k = i >> 7;
    int b = i & 127;
    At[i] = x[b * DD + idx0[k]];
}

// ---------------------------------------------------------------------------
// fp64-accumulate GEMM with fused A-gather:
//   parts[split][n][b] += sum_{k in split} src[row(k), b] * W[n, k]
// src is [row][b] layout (At for layer 0, meanT for layers >= 1).
// row(k) = k for layer 0 (already gathered), idx[k] otherwise.
// ---------------------------------------------------------------------------
__global__ __launch_bounds__(256) void gemm64_kernel(
    const float* __restrict__ srcT,   // [rows][BB] fp32 (values exact)
    const int*   __restrict__ idx,    // nullptr => identity rows
    const float* __restrict__ Wl,     // W + l*NN*DD, row-major [n][k]
    double*      __restrict__ parts)  // [NSPLIT][NN][BB]
{
    __shared__ double Ab[KC * BB];        // 32 KB  [kk][b]
    __shared__ double Wd[NTILE * KC];     //  8 KB  [j][kk]

    const int t     = threadIdx.x;
    const int split = blockIdx.x;
    const int n0    = blockIdx.y * NTILE;
    const int kbase = split * KRANGE;
    const int wave  = t >> 6;
    const int lane  = t & 63;
    const int j0    = wave * 8;           // this wave's n sub-tile

    double acc[16];                        // [b_pair(2)][j(8)]
    #pragma unroll
    for (int i = 0; i < 16; ++i) acc[i] = 0.0;

    for (int kc = 0; kc < KRANGE; kc += KC) {
        const int k0 = kbase + kc;
        __syncthreads();   // protect LDS from previous iteration's readers

        // --- stage A chunk: KC*BB = 4096 floats, 4 float4 per thread ---
        #pragma unroll
        for (int r = 0; r < 4; ++r) {
            int i4 = r * 256 + t;               // float4 index in chunk
            int kk = i4 >> 5;                   // 32 float4 per k-row
            int b4 = i4 & 31;
            int row = idx ? idx[k0 + kk] : (k0 + kk);
            float4 v = *(const float4*)(srcT + (size_t)row * BB + b4 * 4);
            double2* dst = (double2*)(Ab + kk * BB + b4 * 4);
            dst[0] = make_double2((double)v.x, (double)v.y);
            dst[1] = make_double2((double)v.z, (double)v.w);
        }
        // --- stage W chunk: NTILE*KC = 1024 floats, 1 float4 per thread ---
        {
            int j  = t >> 3;                    // 0..31
            int k4 = t & 7;                     // 0..7 (KC/4)
            float4 v = *(const float4*)(Wl + (size_t)(n0 + j) * DD + k0 + k4 * 4);
            double2* dst = (double2*)(Wd + j * KC + k4 * 4);
            dst[0] = make_double2((double)v.x, (double)v.y);
            dst[1] = make_double2((double)v.z, (double)v.w);
        }
        __syncthreads();

        // --- inner product: 2 b x 8 n per lane, fp64 FMAs ---
        #pragma unroll 4
        for (int kk = 0; kk < KC; ++kk) {
            double2 a = *(const double2*)(Ab + kk * BB + 2 * lane);
            #pragma unroll
            for (int j = 0; j < 8; ++j) {
                double w = Wd[(j0 + j) * KC + kk];
                acc[j]     += a.x * w;
                acc[8 + j] += a.y * w;
            }
        }
    }

    // write partials: parts[split][n][b], b = 2*lane, 2*lane+1
    #pragma unroll
    for (int j = 0; j < 8; ++j) {
        int n = n0 + j0 + j;
        size_t o = ((size_t)split * NN + n) * BB + 2 * lane;
        *(double2*)(parts + o) = make_double2(acc[j], acc[8 + j]);
    }
}

// ---------------------------------------------------------------------------
// Spike-count scan: avg = sum of K-split partials (fixed order, deterministic),
// then T steps of { m += avg; if (m > thr) { c++; m -= thr; } }.
// Layers 0-2 write meanT = c/T; layer 3 writes cntT = c.
// ---------------------------------------------------------------------------
__global__ __launch_bounds__(256) void spike_kernel(
    const double* __restrict__ parts, const float* __restrict__ thresholds,
    int l, const int* __restrict__ Tptr,
    float* __restrict__ meanT, float* __restrict__ cntT)
{
    int i = blockIdx.x * 256 + threadIdx.x;   // over NN*BB
    double avg = 0.0;
    #pragma unroll
    for (int s = 0; s < NSPLIT; ++s)
        avg += parts[(size_t)s * NN * BB + i];

    const double thr = (double)thresholds[l];
    const int T = *Tptr;
    double m = 0.0;
    int c = 0;
    for (int t = 0; t < T; ++t) {
        m += avg;
        if (m > thr) { c++; m -= thr; }
    }
    if (l == LL - 1) cntT[i] = (float)c;
    else             meanT[i] = (float)c / (float)T;
}

// ---------------------------------------------------------------------------
// Output gather: out[b, o] = cntT[out_idx[o]][b]
// ---------------------------------------------------------------------------
__global__ __launch_bounds__(256) void out_kernel(
    const float* __restrict__ cntT, const int* __restrict__ out_idx,
    float* __restrict__ out)
{
    int i = blockIdx.x * 256 + threadIdx.x;   // over BB*OUTN
    int b = i >> 10;
    int o = i & 1023;
    out[i] = cntT[(size_t)out_idx[o] * BB + b];
}

extern "C" void kernel_launch(void* const* d_in, const int* in_sizes, int n_in,
                              void* d_out, int out_size, void* d_ws, size_t ws_size,
                              hipStream_t stream)
{
    const float* x     = (const float*)d_in[0];   // [B, D]
    const float* W     = (const float*)d_in[1];   // [L, N, D]
    const float* thr   = (const float*)d_in[2];   // [L]
    const int*   axon  = (const int*)d_in[3];     // [L, D]
    const int*   oidx  = (const int*)d_in[4];     // [OUT]
    const int*   Tptr  = (const int*)d_in[5];     // scalar T
    float* out = (float*)d_out;

    char* ws = (char*)d_ws;
    float*  At    = (float*)ws;                        // 1 MB  [D][B]
    float*  meanT = (float*)(ws + (1u << 20));         // 1 MB  [N][B]
    float*  cntT  = (float*)(ws + (2u << 20));         // 1 MB  [N][B]
    double* parts = (double*)(ws + (3u << 20));        // 16 MB [NSPLIT][N][B]

    // Layer 0 gathered input, transposed to [k][b]
    gather0_kernel<<<(DD * BB) / 256, 256, 0, stream>>>(x, axon, At);

    for (int l = 0; l < LL; ++l) {
        const float* srcT = (l == 0) ? At : meanT;
        const int*   idx  = (l == 0) ? nullptr : (axon + (size_t)l * DD);
        gemm64_kernel<<<dim3(NSPLIT, NN / NTILE), 256, 0, stream>>>(
            srcT, idx, W + (size_t)l * NN * DD, parts);
        spike_kernel<<<(NN * BB) / 256, 256, 0, stream>>>(
            parts, thr, l, Tptr, meanT, cntT);
    }

    out_kernel<<<(BB * OUTN) / 256, 256, 0, stream>>>(cntT, oidx, out);
}

// Round 2
// 291.077 us; speedup vs baseline: 1.0311x; 1.0311x over previous
//
#include <hip/hip_runtime.h>

// Problem constants
#define BB   128
#define DD   2048
#define NN   2048
#define LL   4
#define OUTN 1024
#define NB   (NN * BB)     // elements per [n][b] plane
#define KC   16            // k-chunk staged in LDS

// ---------------------------------------------------------------------------
// Layer-0 transpose-gather: At[k][b] = x[b, axon_idx0[k]]  (fp32, values exact)
// ---------------------------------------------------------------------------
__global__ __launch_bounds__(256) void gather0_kernel(
    const float* __restrict__ x, const int* __restrict__ idx0,
    float* __restrict__ At)
{
    int i = blockIdx.x * 256 + threadIdx.x;   // over DD*BB
    int k = i >> 7;
    int b = i & 127;
    At[i] = x[b * DD + idx0[k]];
}

// ---------------------------------------------------------------------------
// fp64-accumulate GEMM, lane-owns-n layout.
// Block: 256 thr = 4 waves. Block tile: 128 n x 64 b x krange k.
//   wave w: b-subtile [b0 + 16w, +16), lane owns n-pair n0 + 2*lane (+0/1).
// Per kk: W per-lane ds_read_b128 (Wd[kk][2*lane]); A via 8 broadcast b128
// reads (wave-uniform addr, conflict-free); 32 fp64 FMAs.
// ---------------------------------------------------------------------------
__global__ __launch_bounds__(256, 3) void gemm64_kernel(
    const float* __restrict__ srcT,   // [rows(2048)][BB] fp32 (exact values)
    const int*   __restrict__ idx,    // nullptr => identity rows
    const float* __restrict__ Wl,     // row-major [n][k]
    double*      __restrict__ parts,  // [nsplit][NN][BB]
    int krange)
{
    __shared__ __align__(16) double Ab[KC * 64];    //  8 KB  [kk][b(64)]
    __shared__ __align__(16) double Wd[KC * 128];   // 16 KB  [kk][n(128)]

    const int t     = threadIdx.x;
    const int tile  = blockIdx.x;            // 0..31
    const int split = blockIdx.y;
    const int n0    = (tile >> 1) * 128;
    const int b0    = (tile & 1) * 64;
    const int k0b   = split * krange;
    const int wq    = t >> 6;
    const int lane  = t & 63;
    const int bw0   = wq * 16;               // wave's b offset within block tile

    double acc[32];                          // acc[2*bi + p], p = n-pair member
    #pragma unroll
    for (int i = 0; i < 32; ++i) acc[i] = 0.0;

    // staging decomposition
    const int s_kk = t >> 4, s_b4 = t & 15;  // A: one float4 per thread
    const int w_n  = t >> 1, w_h  = t & 1;   // W: two float4 per thread

    float4 aReg, wReg0, wReg1;

    // prologue: load chunk 0 into regs
    {
        int row = idx ? idx[k0b + s_kk] : (k0b + s_kk);
        aReg = *(const float4*)(srcT + (size_t)row * BB + b0 + 4 * s_b4);
        const float* wp = Wl + (size_t)(n0 + w_n) * DD + k0b + 8 * w_h;
        wReg0 = *(const float4*)wp;
        wReg1 = *(const float4*)(wp + 4);
    }

    const int nchunk = krange / KC;
    for (int c = 0; c < nchunk; ++c) {
        __syncthreads();                     // previous chunk's readers done
        // regs -> LDS (with fp32->fp64 cvt)
        {
            double2* ad = (double2*)(Ab + s_kk * 64 + 4 * s_b4);
            ad[0] = make_double2((double)aReg.x, (double)aReg.y);
            ad[1] = make_double2((double)aReg.z, (double)aReg.w);
            double* wbase = Wd + w_n;
            int kk8 = 8 * w_h;
            wbase[(kk8 + 0) * 128] = (double)wReg0.x;
            wbase[(kk8 + 1) * 128] = (double)wReg0.y;
            wbase[(kk8 + 2) * 128] = (double)wReg0.z;
            wbase[(kk8 + 3) * 128] = (double)wReg0.w;
            wbase[(kk8 + 4) * 128] = (double)wReg1.x;
            wbase[(kk8 + 5) * 128] = (double)wReg1.y;
            wbase[(kk8 + 6) * 128] = (double)wReg1.z;
            wbase[(kk8 + 7) * 128] = (double)wReg1.w;
        }
        __syncthreads();
        // prefetch next chunk into regs (overlaps with compute below)
        if (c + 1 < nchunk) {
            int k0 = k0b + (c + 1) * KC;
            int row = idx ? idx[k0 + s_kk] : (k0 + s_kk);
            aReg = *(const float4*)(srcT + (size_t)row * BB + b0 + 4 * s_b4);
            const float* wp = Wl + (size_t)(n0 + w_n) * DD + k0 + 8 * w_h;
            wReg0 = *(const float4*)wp;
            wReg1 = *(const float4*)(wp + 4);
        }
        // compute chunk
        #pragma unroll
        for (int kk = 0; kk < KC; ++kk) {
            double2 w2 = *(const double2*)(Wd + kk * 128 + 2 * lane);
            const double* arow = Ab + kk * 64 + bw0;
            #pragma unroll
            for (int bi = 0; bi < 16; bi += 2) {
                double2 a = *(const double2*)(arow + bi);
                acc[2 * bi + 0] += w2.x * a.x;
                acc[2 * bi + 1] += w2.y * a.x;
                acc[2 * bi + 2] += w2.x * a.y;
                acc[2 * bi + 3] += w2.y * a.y;
            }
        }
    }

    // store: n = n0 + 2*lane + p ; b = b0 + bw0 + bi
    #pragma unroll
    for (int p = 0; p < 2; ++p) {
        size_t base = ((size_t)split * NN + (n0 + 2 * lane + p)) * BB + b0 + bw0;
        #pragma unroll
        for (int bi = 0; bi < 16; bi += 2)
            *(double2*)(parts + base + bi) =
                make_double2(acc[2 * bi + p], acc[2 * bi + 2 + p]);
    }
}

// ---------------------------------------------------------------------------
// Spike-count scan (deterministic fixed-order split reduction), 2 elems/thread
// for ILP on the dependent fp64 chain.
// ---------------------------------------------------------------------------
__global__ __launch_bounds__(256) void spike_kernel(
    const double* __restrict__ parts, const float* __restrict__ thresholds,
    int l, const int* __restrict__ Tptr,
    float* __restrict__ meanT, float* __restrict__ cntT, int nsplit)
{
    int i0 = blockIdx.x * 256 + threadIdx.x;   // 0 .. NB/2-1
    int i1 = i0 + NB / 2;
    double a0 = 0.0, a1 = 0.0;
    for (int s = 0; s < nsplit; ++s) {
        a0 += parts[(size_t)s * NB + i0];
        a1 += parts[(size_t)s * NB + i1];
    }
    const double thr = (double)thresholds[l];
    const int T = *Tptr;
    double m0 = 0.0, m1 = 0.0;
    int c0 = 0, c1 = 0;
    for (int t = 0; t < T; ++t) {
        m0 += a0;
        m1 += a1;
        if (m0 > thr) { c0++; m0 -= thr; }
        if (m1 > thr) { c1++; m1 -= thr; }
    }
    if (l == LL - 1) {
        cntT[i0] = (float)c0;
        cntT[i1] = (float)c1;
    } else {
        meanT[i0] = (float)c0 / (float)T;   // exact in fp32 (T=64)
        meanT[i1] = (float)c1 / (float)T;
    }
}

// ---------------------------------------------------------------------------
// Output gather: out[b, o] = cntT[out_idx[o]][b]
// ---------------------------------------------------------------------------
__global__ __launch_bounds__(256) void out_kernel(
    const float* __restrict__ cntT, const int* __restrict__ out_idx,
    float* __restrict__ out)
{
    int i = blockIdx.x * 256 + threadIdx.x;   // over BB*OUTN
    int b = i >> 10;
    int o = i & 1023;
    out[i] = cntT[(size_t)out_idx[o] * BB + b];
}

extern "C" void kernel_launch(void* const* d_in, const int* in_sizes, int n_in,
                              void* d_out, int out_size, void* d_ws, size_t ws_size,
                              hipStream_t stream)
{
    const float* x    = (const float*)d_in[0];
    const float* W    = (const float*)d_in[1];
    const float* thr  = (const float*)d_in[2];
    const int*   axon = (const int*)d_in[3];
    const int*   oidx = (const int*)d_in[4];
    const int*   Tptr = (const int*)d_in[5];
    float* out = (float*)d_out;

    char* ws = (char*)d_ws;
    float*  At    = (float*)ws;                    // 1 MB  [D][B] fp32
    float*  meanT = (float*)(ws + (1u << 20));     // 1 MB  [N][B] fp32 (c/T exact)
    float*  cntT  = (float*)(ws + (2u << 20));     // 1 MB  [N][B] fp32
    double* parts = (double*)(ws + (3u << 20));    // nsplit * 2 MB

    // adaptive K-split: largest power of 2 <= 16 whose parts fit in ws
    int nsplit = 16;
    while (nsplit > 1 &&
           (size_t)nsplit * NB * sizeof(double) + (3u << 20) > ws_size)
        nsplit >>= 1;
    const int krange = DD / nsplit;

    gather0_kernel<<<(DD * BB) / 256, 256, 0, stream>>>(x, axon, At);

    for (int l = 0; l < LL; ++l) {
        const float* srcT = (l == 0) ? At : meanT;
        const int*   idx  = (l == 0) ? nullptr : (axon + (size_t)l * DD);
        gemm64_kernel<<<dim3(32, nsplit), 256, 0, stream>>>(
            srcT, idx, W + (size_t)l * NN * DD, parts, krange);
        spike_kernel<<<NB / 512, 256, 0, stream>>>(
            parts, thr, l, Tptr, meanT, cntT, nsplit);
    }

    out_kernel<<<(BB * OUTN) / 256, 256, 0, stream>>>(cntT, oidx, out);
}

// Round 4
// 242.976 us; speedup vs baseline: 1.2352x; 1.1980x over previous
//
#include <hip/hip_runtime.h>

// Problem constants
#define BB   128
#define DD   2048
#define NN   2048
#define LL   4
#define OUTN 1024
#define NB   (NN * BB)
#define KC   32            // k per LDS chunk
#define PADW 34            // doubles per n-row in LDS W tile (32 + 2 pad)

typedef double double4v __attribute__((ext_vector_type(4)));

// ---------------------------------------------------------------------------
// Layer-0 transpose-gather: At[k][b] = x[b, axon_idx0[k]]
// ---------------------------------------------------------------------------
__global__ __launch_bounds__(256) void gather0_kernel(
    const float* __restrict__ x, const int* __restrict__ idx0,
    float* __restrict__ At)
{
    int i = blockIdx.x * 256 + threadIdx.x;   // over DD*BB
    int k = i >> 7;
    int b = i & 127;
    At[i] = x[b * DD + idx0[k]];
}

// ---------------------------------------------------------------------------
// fp64 MFMA GEMM: parts[split][n][b] = sum_k W[n][k] * src[row(k)][b]
// Block 256 thr = 4 waves. Block tile: n=64, b=64 (wave wq: b = 16*wq..+16).
// W staged in LDS fp64 (padded); src read per-lane from global (L2-resident).
// D-fragment layout is DISCOVERED AT RUNTIME via two probe MFMAs, so the
// store is correct for any C/D register mapping of v_mfma_f64_16x16x4_f64.
// ---------------------------------------------------------------------------
__global__ __launch_bounds__(256, 4) void gemm_mfma64(
    const float* __restrict__ srcT,   // [row(2048)][BB] fp32
    const int*   __restrict__ idx,    // nullptr => identity rows
    const float* __restrict__ Wl,     // [n][k] row-major
    double*      __restrict__ parts,  // [nsplit][NN][BB]
    int krange)
{
    __shared__ __align__(16) double Wq[64 * PADW];   // 17.4 KB

    const int t     = threadIdx.x;
    const int nsup  = blockIdx.x;          // n / 64
    const int bsup  = blockIdx.y;          // b / 64
    const int split = blockIdx.z;
    const int n0b   = nsup * 64;
    const int k0s   = split * krange;
    const int wq    = t >> 6;
    const int lane  = t & 63;
    const int q     = lane >> 4;           // assumed k-quad
    const int c     = lane & 15;           // assumed m (A) / n (B) coordinate
    const int b0w   = bsup * 64 + wq * 16;

    // ---- runtime D-layout probe ----
    // pr: A[m][k] = m/4 (all lanes of assumed-row m), B = ones -> D[m][n] = m
    // pc: A = 1/4, B[k][n] = n -> D[m][n] = n
    double4v pr = {0., 0., 0., 0.}, pc = {0., 0., 0., 0.};
    pr = __builtin_amdgcn_mfma_f64_16x16x4f64(0.25 * (double)c, 1.0, pr, 0, 0, 0);
    pc = __builtin_amdgcn_mfma_f64_16x16x4f64(0.25, (double)c, pc, 0, 0, 0);
    int rowD[4], colD[4];
    #pragma unroll
    for (int r = 0; r < 4; ++r) {
        rowD[r] = (int)(pr[r] + 0.25);     // true n-offset within 16x16 tile
        colD[r] = (int)(pc[r] + 0.25);     // true b-offset within wave tile
    }

    // staging decomposition: thread stages rows sn and sn+32, float4 sm
    const int sn = t >> 3;                 // 0..31
    const int sm = t & 7;                  // 0..7

    double4v acc[4] = {{0.,0.,0.,0.},{0.,0.,0.,0.},{0.,0.,0.,0.},{0.,0.,0.,0.}};

    // ---- prologue: chunk 0 A regs + B regs ----
    float4 a0 = *(const float4*)(Wl + (size_t)(n0b + sn) * DD + k0s + 4 * sm);
    float4 a1 = *(const float4*)(Wl + (size_t)(n0b + sn + 32) * DD + k0s + 4 * sm);
    float bF[8];
    #pragma unroll
    for (int j = 0; j < 8; ++j) {
        int k = k0s + 4 * j + q;
        int row = idx ? idx[k] : k;
        bF[j] = srcT[(size_t)row * BB + b0w + c];
    }

    const int nchunk = krange / KC;
    for (int ch = 0; ch < nchunk; ++ch) {
        __syncthreads();                    // previous chunk's readers done
        // stage A (cvt fp32->fp64): k_local = 4*sm + i stored at col sm + 8*i
        {
            const float* f0 = (const float*)&a0;
            const float* f1 = (const float*)&a1;
            double* w0 = Wq + sn * PADW + sm;
            double* w1 = Wq + (sn + 32) * PADW + sm;
            #pragma unroll
            for (int i = 0; i < 4; ++i) {
                w0[i * 8] = (double)f0[i];
                w1[i * 8] = (double)f1[i];
            }
        }
        // prefetch next A chunk into regs
        if (ch + 1 < nchunk) {
            const float* p = Wl + (size_t)(n0b + sn) * DD + k0s + (ch + 1) * KC + 4 * sm;
            a0 = *(const float4*)p;
            a1 = *(const float4*)(p + (size_t)32 * DD);
        }
        __syncthreads();                    // W tile visible

        // prefetch next B chunk into regs (VMEM, overlaps compute)
        float bN[8];
        if (ch + 1 < nchunk) {
            int k0n = k0s + (ch + 1) * KC;
            #pragma unroll
            for (int j = 0; j < 8; ++j) {
                int k = k0n + 4 * j + q;
                int row = idx ? idx[k] : k;
                bN[j] = srcT[(size_t)row * BB + b0w + c];
            }
        }

        // compute: k_local = 4*(2*jp + h) + q, cols 8q + 2jp (+1)
        #pragma unroll
        for (int jp = 0; jp < 4; ++jp) {
            double2 wf[4];
            #pragma unroll
            for (int tt = 0; tt < 4; ++tt)
                wf[tt] = *(const double2*)(Wq + (16 * tt + c) * PADW + q * 8 + 2 * jp);
            double bv0 = (double)bF[2 * jp];
            double bv1 = (double)bF[2 * jp + 1];
            #pragma unroll
            for (int tt = 0; tt < 4; ++tt)
                acc[tt] = __builtin_amdgcn_mfma_f64_16x16x4f64(wf[tt].x, bv0, acc[tt], 0, 0, 0);
            #pragma unroll
            for (int tt = 0; tt < 4; ++tt)
                acc[tt] = __builtin_amdgcn_mfma_f64_16x16x4f64(wf[tt].y, bv1, acc[tt], 0, 0, 0);
        }
        if (ch + 1 < nchunk) {
            #pragma unroll
            for (int j = 0; j < 8; ++j) bF[j] = bN[j];
        }
    }

    // store via probed layout: n = n0b + 16*tt + rowD[r], b = b0w + colD[r]
    #pragma unroll
    for (int tt = 0; tt < 4; ++tt) {
        #pragma unroll
        for (int r = 0; r < 4; ++r) {
            int n = n0b + 16 * tt + rowD[r];
            size_t o = ((size_t)split * NN + n) * BB + b0w + colD[r];
            parts[o] = acc[tt][r];
        }
    }
}

// ---------------------------------------------------------------------------
// Spike-count scan (deterministic fixed-order split reduction), 2 elems/thread.
// ---------------------------------------------------------------------------
__global__ __launch_bounds__(256) void spike_kernel(
    const double* __restrict__ parts, const float* __restrict__ thresholds,
    int l, const int* __restrict__ Tptr,
    float* __restrict__ meanT, float* __restrict__ cntT, int nsplit)
{
    int i0 = blockIdx.x * 256 + threadIdx.x;   // 0 .. NB/2-1
    int i1 = i0 + NB / 2;
    double a0 = 0.0, a1 = 0.0;
    for (int s = 0; s < nsplit; ++s) {
        a0 += parts[(size_t)s * NB + i0];
        a1 += parts[(size_t)s * NB + i1];
    }
    const double thr = (double)thresholds[l];
    const int T = *Tptr;
    double m0 = 0.0, m1 = 0.0;
    int c0 = 0, c1 = 0;
    for (int t = 0; t < T; ++t) {
        m0 += a0;
        m1 += a1;
        if (m0 > thr) { c0++; m0 -= thr; }
        if (m1 > thr) { c1++; m1 -= thr; }
    }
    if (l == LL - 1) {
        cntT[i0] = (float)c0;
        cntT[i1] = (float)c1;
    } else {
        meanT[i0] = (float)c0 / (float)T;   // exact in fp32 (T=64)
        meanT[i1] = (float)c1 / (float)T;
    }
}

// ---------------------------------------------------------------------------
// Output gather: out[b, o] = cntT[out_idx[o]][b]
// ---------------------------------------------------------------------------
__global__ __launch_bounds__(256) void out_kernel(
    const float* __restrict__ cntT, const int* __restrict__ out_idx,
    float* __restrict__ out)
{
    int i = blockIdx.x * 256 + threadIdx.x;   // over BB*OUTN
    int b = i >> 10;
    int o = i & 1023;
    out[i] = cntT[(size_t)out_idx[o] * BB + b];
}

extern "C" void kernel_launch(void* const* d_in, const int* in_sizes, int n_in,
                              void* d_out, int out_size, void* d_ws, size_t ws_size,
                              hipStream_t stream)
{
    const float* x    = (const float*)d_in[0];
    const float* W    = (const float*)d_in[1];
    const float* thr  = (const float*)d_in[2];
    const int*   axon = (const int*)d_in[3];
    const int*   oidx = (const int*)d_in[4];
    const int*   Tptr = (const int*)d_in[5];
    float* out = (float*)d_out;

    char* ws = (char*)d_ws;
    float*  At    = (float*)ws;                    // 1 MB  [D][B]
    float*  meanT = (float*)(ws + (1u << 20));     // 1 MB  [N][B]
    float*  cntT  = (float*)(ws + (2u << 20));     // 1 MB  [N][B]
    double* parts = (double*)(ws + (3u << 20));    // nsplit * 2 MB

    // adaptive K-split: largest power of 2 <= 16 whose parts fit in ws
    int nsplit = 16;
    while (nsplit > 1 &&
           (size_t)nsplit * NB * sizeof(double) + (3u << 20) > ws_size)
        nsplit >>= 1;
    const int krange = DD / nsplit;    // multiple of KC for nsplit <= 64

    gather0_kernel<<<(DD * BB) / 256, 256, 0, stream>>>(x, axon, At);

    for (int l = 0; l < LL; ++l) {
        const float* srcT = (l == 0) ? At : meanT;
        const int*   idx  = (l == 0) ? nullptr : (axon + (size_t)l * DD);
        gemm_mfma64<<<dim3(NN / 64, BB / 64, nsplit), 256, 0, stream>>>(
            srcT, idx, W + (size_t)l * NN * DD, parts, krange);
        spike_kernel<<<NB / 512, 256, 0, stream>>>(
            parts, thr, l, Tptr, meanT, cntT, nsplit);
    }

    out_kernel<<<(BB * OUTN) / 256, 256, 0, stream>>>(cntT, oidx, out);
}